// Round 21
// baseline (175.078 us; speedup 1.0000x reference)
//
#include <hip/hip_runtime.h>
#include <math.h>

#define N_NODES 50000
#define FIN 512
#define H1 8
#define D1 128   // H1*C1
#define D2 64
#define MAXD 64                          // padded CSR slots (deg ~Poisson(17), P(>=64)~1e-18)
#define GG 1563                          // gemm1 blocks = ceil(50000/32)
#define EPB 544                          // edges per block = ceil(850000/1563)

typedef __attribute__((ext_vector_type(4))) float f32x4;
typedef __attribute__((ext_vector_type(8))) __bf16 bf16x8;
typedef __attribute__((ext_vector_type(4))) __bf16 bf16x4;

__device__ __forceinline__ void gload_lds16(const void* g, void* l) {
    __builtin_amdgcn_global_load_lds(
        (const __attribute__((address_space(1))) void*)g,
        (__attribute__((address_space(3))) void*)l, 16, 0, 0);
}

// padded elds offset: lane*8 spread to avoid 4-lane bank aliasing (16B-aligned)
__device__ __forceinline__ int epad(int j) { return j * 8 + (j >> 2) * 4; }

// ------- prep: zero cnt, pack W1 (pre-swizzled) + W2 (fragment) -----------
__global__ __launch_bounds__(256) void k_prep(const float* __restrict__ W1,
                                              const float* __restrict__ W2,
                                              __bf16* __restrict__ WpP,
                                              __bf16* __restrict__ Wp2,
                                              int* __restrict__ cnt) {
    int idx = blockIdx.x * 256 + threadIdx.x;   // 65536 = 512*128
    int k = idx >> 7, col = idx & 127;
    int region = k >> 6;                        // K-step (64 k's)
    int kgl = (k >> 3) & 7;                     // kgrp within region
    int u_out = (kgl * 128 + col) ^ (kgl & 3);
    WpP[region * 8192 + u_out * 8 + (k & 7)] = (__bf16)W1[idx];
    if (idx < N_NODES) cnt[idx] = 0;
    if (idx < D1 * D2) {
        int k2 = idx >> 6, col2 = idx & 63;
        Wp2[(k2 >> 3) * 512 + col2 * 8 + (k2 & 7)] = (__bf16)W2[idx];
    }
}

// ------- MEGA: every block = GEMM1+att1 then its own 544-edge slice -------
// Edge burst runs after the gemm phase at full-machine parallelism (all
// blocks co-resident) -- no separate edge-block tail.
__global__ __launch_bounds__(256) void k_mega(const float* __restrict__ x,
                                              const __bf16* __restrict__ WpP,
                                              const float* __restrict__ asrc1,
                                              const float* __restrict__ adst1,
                                              __bf16* __restrict__ h1b,
                                              float* __restrict__ as1,
                                              float* __restrict__ ad1,
                                              const int* __restrict__ ei, int E,
                                              int* __restrict__ cnt,
                                              int* __restrict__ srcs) {
    __shared__ __align__(16) __bf16 As[32 * 64];    // 4KB
    __shared__ __align__(16) __bf16 Bs[64 * 128];   // 16KB
    const int t = threadIdx.x;

    // ---------------- GEMM1 phase ----------------
    const int l = t & 63;
    const int w = t >> 6;
    const int wr = (w >> 1) * 16, wc = (w & 1) * 64;
    const int n0 = blockIdx.x * 32;

    f32x4 acc[4];
    #pragma unroll
    for (int j = 0; j < 4; ++j) acc[j] = (f32x4){0.f, 0.f, 0.f, 0.f};

    const int arow = t >> 4;            // staging row base (0..15)
    const int ak4  = (t & 15) * 4;      // staging k offset (elements)

    for (int s = 0; s < 8; ++s) {
        const int k0 = s * 64;
        {
            const __bf16* gsrc = WpP + (size_t)s * 8192;
            #pragma unroll
            for (int i = 0; i < 4; ++i) {
                int ubase = w * 256 + i * 64;              // wave-uniform unit
                gload_lds16(gsrc + (ubase + l) * 8, Bs + ubase * 8);
            }
        }
        #pragma unroll
        for (int i = 0; i < 2; ++i) {
            int row = arow + i * 16;
            int grow = n0 + row;
            float4 f = {0.f, 0.f, 0.f, 0.f};
            if (grow < N_NODES)
                f = *(const float4*)(x + (size_t)grow * FIN + k0 + ak4);
            bf16x4 v = {(__bf16)f.x, (__bf16)f.y, (__bf16)f.z, (__bf16)f.w};
            int eo = (row * 64 + ak4) ^ ((row & 7) << 3);
            *(bf16x4*)(As + eo) = v;
        }
        __syncthreads();                 // drains vmcnt + lgkmcnt
        #pragma unroll
        for (int ks = 0; ks < 2; ++ks) {
            bf16x8 af, bfr[4];
            {
                int row = wr + (l & 15);
                int eo = (row * 64 + ks * 32 + (l >> 4) * 8) ^ ((row & 7) << 3);
                af = *(const bf16x8*)(As + eo);
            }
            #pragma unroll
            for (int fn = 0; fn < 4; ++fn) {
                int col = wc + fn * 16 + (l & 15);
                int kg = ks * 4 + (l >> 4);
                int u = (kg * 128 + col) ^ (kg & 3);
                bfr[fn] = *(const bf16x8*)(Bs + u * 8);
            }
            #pragma unroll
            for (int fn = 0; fn < 4; ++fn)
                acc[fn] = __builtin_amdgcn_mfma_f32_16x16x32_bf16(
                    af, bfr[fn], acc[fn], 0, 0, 0);
        }
        __syncthreads();
    }
    #pragma unroll
    for (int reg = 0; reg < 4; ++reg) {
        int row = n0 + wr + (l >> 4) * 4 + reg;
        if (row >= N_NODES) continue;
        #pragma unroll
        for (int fn = 0; fn < 4; ++fn) {
            int col = wc + fn * 16 + (l & 15);
            h1b[(size_t)row * D1 + col] = (__bf16)acc[fn][reg];
        }
    }
    const int c16 = l & 15;
    float av[4], dv[4];
    #pragma unroll
    for (int fn = 0; fn < 4; ++fn) {
        int head = (wc >> 4) + fn;
        av[fn] = asrc1[head * 16 + c16];
        dv[fn] = adst1[head * 16 + c16];
    }
    #pragma unroll
    for (int reg = 0; reg < 4; ++reg) {
        #pragma unroll
        for (int fn = 0; fn < 4; ++fn) {
            float vs = acc[fn][reg] * av[fn];
            float vd = acc[fn][reg] * dv[fn];
            #pragma unroll
            for (int mk = 1; mk <= 8; mk <<= 1) {
                vs += __shfl_xor(vs, mk, 64);
                vd += __shfl_xor(vd, mk, 64);
            }
            if (c16 == 0) {
                int row = n0 + wr + (l >> 4) * 4 + reg;
                if (row < N_NODES) {
                    int head = (wc >> 4) + fn;
                    as1[(size_t)row * 8 + head] = vs;
                    ad1[(size_t)row * 8 + head] = vd;
                }
            }
        }
    }

    // ---------------- edge phase: this block's 544-edge slice -------------
    const int ET = E + N_NODES;
    const int eb0 = blockIdx.x * EPB;
    const int eb1 = min(eb0 + EPB, ET);
    #pragma unroll
    for (int i = 0; i < 3; ++i) {
        int e = eb0 + i * 256 + t;
        if (e < eb1) {
            int s = (e < E) ? ei[e] : (e - E);
            int d = (e < E) ? ei[E + e] : (e - E);
            int r = atomicAdd(&cnt[d], 1);
            if (r < MAXD)
                __builtin_nontemporal_store(s, &srcs[(size_t)d * MAXD + r]);
        }
    }
}

// ------- aggregation layer 1: fused edge-exp + gather, wave/node ----------
// padded CSR: segment base n*MAXD, count cnt[n] (always <= 64 -> one chunk)
__global__ __launch_bounds__(256) void k_agg1(const int* __restrict__ cnt,
                                              const int* __restrict__ srcs,
                                              const float* __restrict__ as1,
                                              const float* __restrict__ ad1,
                                              const __bf16* __restrict__ h1b,
                                              const float* __restrict__ b1,
                                              __bf16* __restrict__ r1b) {
    __shared__ float elds[4][576];
    const int w = threadIdx.x >> 6;
    const int l = threadIdx.x & 63;
    const int q = l >> 4;                      // edge slot within quad
    const int c8 = (l & 15) * 8;               // 8 channels per lane
    const int h = (l & 15) >> 1;               // head of this channel group
    const int n = blockIdx.x * 4 + w;          // 12500 blocks exactly
    const int p0 = n * MAXD;
    const int m = min(cnt[n], MAXD);
    float adv[8];
    #pragma unroll
    for (int i = 0; i < 8; ++i) adv[i] = ad1[(size_t)n * 8 + i];
    float ac[8] = {0.f, 0.f, 0.f, 0.f, 0.f, 0.f, 0.f, 0.f};
    float se = 0.f;
    for (int base = 0; base < m; base += 64) {
        const int cm = min(64, m - base);
        asm volatile("s_waitcnt lgkmcnt(0)" ::: "memory");   // prior reads done
        int my_s = 0;
        if (l < cm) {
            my_s = srcs[p0 + base + l];
            const float4* ap = (const float4*)(as1 + (size_t)my_s * 8);
            float4 A0 = ap[0], A1 = ap[1];
            float uu[8] = {A0.x + adv[0], A0.y + adv[1], A0.z + adv[2], A0.w + adv[3],
                           A1.x + adv[4], A1.y + adv[5], A1.z + adv[6], A1.w + adv[7]};
            float ee[8];
            #pragma unroll
            for (int i = 0; i < 8; ++i) {
                float u = uu[i];
                u = (u > 0.f) ? u : 0.2f * u;
                ee[i] = __expf(u);
            }
            int eo = epad(l);
            *(float4*)(&elds[w][eo])     = make_float4(ee[0], ee[1], ee[2], ee[3]);
            *(float4*)(&elds[w][eo + 4]) = make_float4(ee[4], ee[5], ee[6], ee[7]);
        }
        asm volatile("s_waitcnt lgkmcnt(0)" ::: "memory");   // writes visible
        #pragma unroll 2
        for (int j4 = 0; j4 < cm; j4 += 4) {
            int j = j4 + q;
            bool ok = j < cm;
            int jj = ok ? j : 0;
            int s = __shfl(my_s, jj, 64);
            float ee = elds[w][epad(jj) + h];
            if (!ok) ee = 0.f;
            se += ee;
            bf16x8 hv = *(const bf16x8*)(h1b + (size_t)s * D1 + c8);
            #pragma unroll
            for (int i = 0; i < 8; ++i) ac[i] += ee * (float)hv[i];
        }
    }
    #pragma unroll
    for (int mk = 16; mk <= 32; mk <<= 1) {
        #pragma unroll
        for (int i = 0; i < 8; ++i) ac[i] += __shfl_xor(ac[i], mk, 64);
        se += __shfl_xor(se, mk, 64);
    }
    if (q == 0) {
        float inv = 1.f / (se + 1e-16f);
        bf16x8 r;
        #pragma unroll
        for (int i = 0; i < 8; ++i)
            r[i] = (__bf16)fmaxf(ac[i] * inv + b1[c8 + i], 0.f);
        *(bf16x8*)(r1b + (size_t)n * D1 + c8) = r;
    }
}

// ------- GEMM2 (MFMA) + fused att2 dots: h2b, as2, ad2 --------------------
__global__ __launch_bounds__(256) void k_gemm2(const __bf16* __restrict__ r1b,
                                               const __bf16* __restrict__ Wp2,
                                               const float* __restrict__ av2,
                                               const float* __restrict__ dv2,
                                               __bf16* __restrict__ h2b,
                                               float* __restrict__ as2,
                                               float* __restrict__ ad2) {
    __shared__ __align__(16) __bf16 As[128 * 128];  // 32KB, XOR-swizzled
    __shared__ __align__(16) __bf16 Bs[128 * 64];   // 16KB, packed+swizzled
    const int t = threadIdx.x;
    const int l = t & 63;
    const int w = t >> 6;
    const int wr = w * 32;
    const int n0 = blockIdx.x * 128;

    const uint4* gb = (const uint4*)Wp2;
    #pragma unroll
    for (int i = 0; i < 4; ++i) {
        int u = t + i * 256;
        uint4 d = gb[u];
        int u2 = u ^ ((u >> 6) & 3);
        *(uint4*)(Bs + u2 * 8) = d;
    }
    #pragma unroll
    for (int i = 0; i < 8; ++i) {
        int u = t + i * 256;
        int row = u >> 4, koff = (u & 15) * 8;
        bf16x8 v = {};
        if (n0 + row < N_NODES)
            v = *(const bf16x8*)(r1b + (size_t)(n0 + row) * D1 + koff);
        int eo = (row * 128 + koff) ^ ((row & 7) << 3);
        *(bf16x8*)(As + eo) = v;
    }
    __syncthreads();

    f32x4 acc[2][4];
    #pragma unroll
    for (int i = 0; i < 2; ++i)
        #pragma unroll
        for (int j = 0; j < 4; ++j) acc[i][j] = (f32x4){0.f, 0.f, 0.f, 0.f};

    #pragma unroll
    for (int ks = 0; ks < 4; ++ks) {
        bf16x8 af[2], bfr[4];
        #pragma unroll
        for (int fm = 0; fm < 2; ++fm) {
            int row = wr + fm * 16 + (l & 15);
            int eo = (row * 128 + ks * 32 + (l >> 4) * 8) ^ ((row & 7) << 3);
            af[fm] = *(const bf16x8*)(As + eo);
        }
        #pragma unroll
        for (int fn = 0; fn < 4; ++fn) {
            int col = fn * 16 + (l & 15);
            int kg = ks * 4 + (l >> 4);
            int u = (kg * 64 + col) ^ (kg & 3);
            bfr[fn] = *(const bf16x8*)(Bs + u * 8);
        }
        #pragma unroll
        for (int fm = 0; fm < 2; ++fm)
            #pragma unroll
            for (int fn = 0; fn < 4; ++fn)
                acc[fm][fn] = __builtin_amdgcn_mfma_f32_16x16x32_bf16(
                    af[fm], bfr[fn], acc[fm][fn], 0, 0, 0);
    }
    #pragma unroll
    for (int fm = 0; fm < 2; ++fm) {
        #pragma unroll
        for (int reg = 0; reg < 4; ++reg) {
            int row = n0 + wr + fm * 16 + (l >> 4) * 4 + reg;
            if (row >= N_NODES) continue;
            #pragma unroll
            for (int fn = 0; fn < 4; ++fn) {
                int col = fn * 16 + (l & 15);
                h2b[(size_t)row * D2 + col] = (__bf16)acc[fm][fn][reg];
            }
        }
    }
    // fused att2
    const int c16 = l & 15;
    float av[4], dv[4];
    #pragma unroll
    for (int fn = 0; fn < 4; ++fn) {
        av[fn] = av2[fn * 16 + c16];
        dv[fn] = dv2[fn * 16 + c16];
    }
    #pragma unroll
    for (int fm = 0; fm < 2; ++fm) {
        #pragma unroll
        for (int reg = 0; reg < 4; ++reg) {
            float vs = 0.f, vd = 0.f;
            #pragma unroll
            for (int fn = 0; fn < 4; ++fn) {
                vs += acc[fm][fn][reg] * av[fn];
                vd += acc[fm][fn][reg] * dv[fn];
            }
            #pragma unroll
            for (int mk = 1; mk <= 8; mk <<= 1) {
                vs += __shfl_xor(vs, mk, 64);
                vd += __shfl_xor(vd, mk, 64);
            }
            if (c16 == 0) {
                int row = n0 + wr + fm * 16 + (l >> 4) * 4 + reg;
                if (row < N_NODES) { as2[row] = vs; ad2[row] = vd; }
            }
        }
    }
}

// ------- aggregation layer 2: fused edge-exp + gather + log_softmax -------
__global__ __launch_bounds__(256) void k_agg2(const int* __restrict__ cnt,
                                              const int* __restrict__ srcs,
                                              const float* __restrict__ as2,
                                              const float* __restrict__ ad2,
                                              const __bf16* __restrict__ h2b,
                                              const float* __restrict__ b2,
                                              float* __restrict__ out) {
    const int w = threadIdx.x >> 6;
    const int l = threadIdx.x & 63;
    const int o = l >> 3;                      // edge slot within octet
    const int c8 = (l & 7) * 8;                // 8 channels per lane
    const int n = blockIdx.x * 4 + w;          // 12500 blocks exactly
    const int p0 = n * MAXD;
    const int m = min(cnt[n], MAXD);
    const float adn = ad2[n];
    float ac[8] = {0.f, 0.f, 0.f, 0.f, 0.f, 0.f, 0.f, 0.f};
    float se = 0.f;
    for (int base = 0; base < m; base += 64) {
        const int cm = min(64, m - base);
        int my_s = 0; float my_e = 0.f;
        if (l < cm) {
            my_s = srcs[p0 + base + l];
            float u = as2[my_s] + adn;
            u = (u > 0.f) ? u : 0.2f * u;
            my_e = __expf(u);
        }
        #pragma unroll 2
        for (int j8 = 0; j8 < cm; j8 += 8) {
            int j = j8 + o;
            bool ok = j < cm;
            int jj = ok ? j : 0;
            int s = __shfl(my_s, jj, 64);
            float ee = __shfl(my_e, jj, 64);
            if (!ok) ee = 0.f;
            se += ee;
            bf16x8 hv = *(const bf16x8*)(h2b + (size_t)s * D2 + c8);
            #pragma unroll
            for (int i = 0; i < 8; ++i) ac[i] += ee * (float)hv[i];
        }
    }
    #pragma unroll
    for (int mk = 8; mk <= 32; mk <<= 1) {
        #pragma unroll
        for (int i = 0; i < 8; ++i) ac[i] += __shfl_xor(ac[i], mk, 64);
        se += __shfl_xor(se, mk, 64);
    }
    float inv = 1.f / (se + 1e-16f);
    float v[8];
    #pragma unroll
    for (int i = 0; i < 8; ++i) v[i] = ac[i] * inv + b2[c8 + i];
    float mx = v[0];
    #pragma unroll
    for (int i = 1; i < 8; ++i) mx = fmaxf(mx, v[i]);
    #pragma unroll
    for (int mk = 1; mk <= 4; mk <<= 1) mx = fmaxf(mx, __shfl_xor(mx, mk, 64));
    float ex = 0.f;
    #pragma unroll
    for (int i = 0; i < 8; ++i) ex += __expf(v[i] - mx);
    #pragma unroll
    for (int mk = 1; mk <= 4; mk <<= 1) ex += __shfl_xor(ex, mk, 64);
    float lse = mx + __logf(ex);
    if (o == 0) {
        f32x4 r0 = {v[0] - lse, v[1] - lse, v[2] - lse, v[3] - lse};
        f32x4 r1 = {v[4] - lse, v[5] - lse, v[6] - lse, v[7] - lse};
        *(f32x4*)(out + (size_t)n * D2 + c8)     = r0;
        *(f32x4*)(out + (size_t)n * D2 + c8 + 4) = r1;
    }
}

extern "C" void kernel_launch(void* const* d_in, const int* in_sizes, int n_in,
                              void* d_out, int out_size, void* d_ws, size_t ws_size,
                              hipStream_t stream) {
    const float* x     = (const float*)d_in[0];
    const int*   ei    = (const int*)d_in[1];
    const float* W1    = (const float*)d_in[2];
    const float* asrc1 = (const float*)d_in[3];
    const float* adst1 = (const float*)d_in[4];
    const float* b1    = (const float*)d_in[5];
    const float* W2    = (const float*)d_in[6];
    const float* asrc2 = (const float*)d_in[7];
    const float* adst2 = (const float*)d_in[8];
    const float* b2    = (const float*)d_in[9];

    const int E  = in_sizes[1] / 2;   // 800000

    // ---- workspace layout ----
    __bf16* r1b = (__bf16*)d_ws;                        // N*128 bf16 (relu1)
    float* fw  = (float*)(r1b + (size_t)N_NODES * D1);
    float* as1  = fw;                                   // N*8
    float* ad1  = as1  + (size_t)N_NODES * H1;          // N*8
    float* as2  = ad1  + (size_t)N_NODES * H1;          // N
    float* ad2  = as2  + N_NODES;                       // N
    int* iw   = (int*)(ad2 + N_NODES);
    int* cnt  = iw;                                     // N
    int* srcs = cnt  + N_NODES;                         // N*MAXD (12.8 MB)
    uintptr_t pa = ((uintptr_t)(srcs + (size_t)N_NODES * MAXD) + 255) & ~(uintptr_t)255;
    __bf16* WpP  = (__bf16*)pa;                         // 512*128 bf16 (pre-swz)
    __bf16* Wp2  = WpP + (size_t)FIN * D1;              // 128*64 bf16
    __bf16* h1b  = Wp2 + (size_t)D1 * D2;               // N*128 bf16
    __bf16* h2b  = h1b + (size_t)N_NODES * D1;          // N*64 bf16

    k_prep   <<<FIN * D1 / 256, 256, 0, stream>>>(W1, W2, WpP, Wp2, cnt);
    k_mega   <<<GG, 256, 0, stream>>>(x, WpP, asrc1, adst1, h1b, as1, ad1,
                                      ei, E, cnt, srcs);
    k_agg1   <<<N_NODES / 4, 256, 0, stream>>>(cnt, srcs, as1, ad1, h1b, b1, r1b);
    k_gemm2  <<<(N_NODES + 127) / 128, 256, 0, stream>>>(r1b, Wp2, asrc2, adst2, h2b, as2, ad2);
    k_agg2   <<<N_NODES / 4, 256, 0, stream>>>(cnt, srcs, as2, ad2, h2b, b2, (float*)d_out);
}

// Round 22
// 134.580 us; speedup vs baseline: 1.3009x; 1.3009x over previous
//
#include <hip/hip_runtime.h>
#include <math.h>

#define N_NODES 50000
#define FIN 512
#define H1 8
#define D1 128   // H1*C1
#define D2 64
#define MAXD 64                          // padded CSR slots (deg ~Poisson(17), P(>=64)~1e-18)
#define GG 1563                          // gemm1 blocks = ceil(50000/32)
#define EB 485                           // edge blocks = 2048 - GG (exactly co-resident)

typedef __attribute__((ext_vector_type(4))) float f32x4;
typedef __attribute__((ext_vector_type(8))) __bf16 bf16x8;
typedef __attribute__((ext_vector_type(4))) __bf16 bf16x4;

__device__ __forceinline__ void gload_lds16(const void* g, void* l) {
    __builtin_amdgcn_global_load_lds(
        (const __attribute__((address_space(1))) void*)g,
        (__attribute__((address_space(3))) void*)l, 16, 0, 0);
}

// padded elds offset: lane*8 spread to avoid 4-lane bank aliasing (16B-aligned)
__device__ __forceinline__ int epad(int j) { return j * 8 + (j >> 2) * 4; }

// ------- prep: zero cnt, pack W1 (pre-swizzled) + W2 (fragment) -----------
__global__ __launch_bounds__(256) void k_prep(const float* __restrict__ W1,
                                              const float* __restrict__ W2,
                                              __bf16* __restrict__ WpP,
                                              __bf16* __restrict__ Wp2,
                                              int* __restrict__ cnt) {
    int idx = blockIdx.x * 256 + threadIdx.x;   // 65536 = 512*128
    int k = idx >> 7, col = idx & 127;
    int region = k >> 6;                        // K-step (64 k's)
    int kgl = (k >> 3) & 7;                     // kgrp within region
    int u_out = (kgl * 128 + col) ^ (kgl & 3);
    WpP[region * 8192 + u_out * 8 + (k & 7)] = (__bf16)W1[idx];
    if (idx < N_NODES) cnt[idx] = 0;
    if (idx < D1 * D2) {
        int k2 = idx >> 6, col2 = idx & 63;
        Wp2[(k2 >> 3) * 512 + col2 * 8 + (k2 & 7)] = (__bf16)W2[idx];
    }
}

// ------- MEGA: blocks [0,GG) = GEMM1+att1; blocks [GG,GG+EB) = edge pass --
// EB chosen so the WHOLE grid (2048 blocks x 20KB LDS) is co-resident:
// edge blocks grid-stride over all edges CONCURRENTLY with the gemm span.
__global__ __launch_bounds__(256) void k_mega(const float* __restrict__ x,
                                              const __bf16* __restrict__ WpP,
                                              const float* __restrict__ asrc1,
                                              const float* __restrict__ adst1,
                                              __bf16* __restrict__ h1b,
                                              float* __restrict__ as1,
                                              float* __restrict__ ad1,
                                              const int* __restrict__ ei, int E,
                                              int* __restrict__ cnt,
                                              int* __restrict__ srcs) {
    __shared__ __align__(16) __bf16 As[32 * 64];    // 4KB
    __shared__ __align__(16) __bf16 Bs[64 * 128];   // 16KB
    const int t = threadIdx.x;

    if (blockIdx.x >= GG) {
        // ------- edge path: hist + padded scatter, grid-stride -------
        const int ET = E + N_NODES;
        const int stride = EB * 256;
        for (int e = (blockIdx.x - GG) * 256 + t; e < ET; e += stride) {
            int s = (e < E) ? ei[e] : (e - E);
            int d = (e < E) ? ei[E + e] : (e - E);
            int r = atomicAdd(&cnt[d], 1);
            if (r < MAXD)
                __builtin_nontemporal_store(s, &srcs[(size_t)d * MAXD + r]);
        }
        return;
    }

    // ---------------- GEMM1 path ----------------
    const int l = t & 63;
    const int w = t >> 6;
    const int wr = (w >> 1) * 16, wc = (w & 1) * 64;
    const int n0 = blockIdx.x * 32;

    f32x4 acc[4];
    #pragma unroll
    for (int j = 0; j < 4; ++j) acc[j] = (f32x4){0.f, 0.f, 0.f, 0.f};

    const int arow = t >> 4;            // staging row base (0..15)
    const int ak4  = (t & 15) * 4;      // staging k offset (elements)

    for (int s = 0; s < 8; ++s) {
        const int k0 = s * 64;
        {
            const __bf16* gsrc = WpP + (size_t)s * 8192;
            #pragma unroll
            for (int i = 0; i < 4; ++i) {
                int ubase = w * 256 + i * 64;              // wave-uniform unit
                gload_lds16(gsrc + (ubase + l) * 8, Bs + ubase * 8);
            }
        }
        #pragma unroll
        for (int i = 0; i < 2; ++i) {
            int row = arow + i * 16;
            int grow = n0 + row;
            float4 f = {0.f, 0.f, 0.f, 0.f};
            if (grow < N_NODES)
                f = *(const float4*)(x + (size_t)grow * FIN + k0 + ak4);
            bf16x4 v = {(__bf16)f.x, (__bf16)f.y, (__bf16)f.z, (__bf16)f.w};
            int eo = (row * 64 + ak4) ^ ((row & 7) << 3);
            *(bf16x4*)(As + eo) = v;
        }
        __syncthreads();                 // drains vmcnt + lgkmcnt
        #pragma unroll
        for (int ks = 0; ks < 2; ++ks) {
            bf16x8 af, bfr[4];
            {
                int row = wr + (l & 15);
                int eo = (row * 64 + ks * 32 + (l >> 4) * 8) ^ ((row & 7) << 3);
                af = *(const bf16x8*)(As + eo);
            }
            #pragma unroll
            for (int fn = 0; fn < 4; ++fn) {
                int col = wc + fn * 16 + (l & 15);
                int kg = ks * 4 + (l >> 4);
                int u = (kg * 128 + col) ^ (kg & 3);
                bfr[fn] = *(const bf16x8*)(Bs + u * 8);
            }
            #pragma unroll
            for (int fn = 0; fn < 4; ++fn)
                acc[fn] = __builtin_amdgcn_mfma_f32_16x16x32_bf16(
                    af, bfr[fn], acc[fn], 0, 0, 0);
        }
        __syncthreads();
    }
    #pragma unroll
    for (int reg = 0; reg < 4; ++reg) {
        int row = n0 + wr + (l >> 4) * 4 + reg;
        if (row >= N_NODES) continue;
        #pragma unroll
        for (int fn = 0; fn < 4; ++fn) {
            int col = wc + fn * 16 + (l & 15);
            h1b[(size_t)row * D1 + col] = (__bf16)acc[fn][reg];
        }
    }
    const int c16 = l & 15;
    float av[4], dv[4];
    #pragma unroll
    for (int fn = 0; fn < 4; ++fn) {
        int head = (wc >> 4) + fn;
        av[fn] = asrc1[head * 16 + c16];
        dv[fn] = adst1[head * 16 + c16];
    }
    #pragma unroll
    for (int reg = 0; reg < 4; ++reg) {
        #pragma unroll
        for (int fn = 0; fn < 4; ++fn) {
            float vs = acc[fn][reg] * av[fn];
            float vd = acc[fn][reg] * dv[fn];
            #pragma unroll
            for (int mk = 1; mk <= 8; mk <<= 1) {
                vs += __shfl_xor(vs, mk, 64);
                vd += __shfl_xor(vd, mk, 64);
            }
            if (c16 == 0) {
                int row = n0 + wr + (l >> 4) * 4 + reg;
                if (row < N_NODES) {
                    int head = (wc >> 4) + fn;
                    as1[(size_t)row * 8 + head] = vs;
                    ad1[(size_t)row * 8 + head] = vd;
                }
            }
        }
    }
}

// ------- aggregation layer 1: fused edge-exp + gather, wave/node ----------
// padded CSR: segment base n*MAXD, count cnt[n] (always <= 64 -> one chunk)
__global__ __launch_bounds__(256) void k_agg1(const int* __restrict__ cnt,
                                              const int* __restrict__ srcs,
                                              const float* __restrict__ as1,
                                              const float* __restrict__ ad1,
                                              const __bf16* __restrict__ h1b,
                                              const float* __restrict__ b1,
                                              __bf16* __restrict__ r1b) {
    __shared__ float elds[4][576];
    const int w = threadIdx.x >> 6;
    const int l = threadIdx.x & 63;
    const int q = l >> 4;                      // edge slot within quad
    const int c8 = (l & 15) * 8;               // 8 channels per lane
    const int h = (l & 15) >> 1;               // head of this channel group
    const int n = blockIdx.x * 4 + w;          // 12500 blocks exactly
    const int p0 = n * MAXD;
    const int m = min(cnt[n], MAXD);
    float adv[8];
    #pragma unroll
    for (int i = 0; i < 8; ++i) adv[i] = ad1[(size_t)n * 8 + i];
    float ac[8] = {0.f, 0.f, 0.f, 0.f, 0.f, 0.f, 0.f, 0.f};
    float se = 0.f;
    for (int base = 0; base < m; base += 64) {
        const int cm = min(64, m - base);
        asm volatile("s_waitcnt lgkmcnt(0)" ::: "memory");   // prior reads done
        int my_s = 0;
        if (l < cm) {
            my_s = srcs[p0 + base + l];
            const float4* ap = (const float4*)(as1 + (size_t)my_s * 8);
            float4 A0 = ap[0], A1 = ap[1];
            float uu[8] = {A0.x + adv[0], A0.y + adv[1], A0.z + adv[2], A0.w + adv[3],
                           A1.x + adv[4], A1.y + adv[5], A1.z + adv[6], A1.w + adv[7]};
            float ee[8];
            #pragma unroll
            for (int i = 0; i < 8; ++i) {
                float u = uu[i];
                u = (u > 0.f) ? u : 0.2f * u;
                ee[i] = __expf(u);
            }
            int eo = epad(l);
            *(float4*)(&elds[w][eo])     = make_float4(ee[0], ee[1], ee[2], ee[3]);
            *(float4*)(&elds[w][eo + 4]) = make_float4(ee[4], ee[5], ee[6], ee[7]);
        }
        asm volatile("s_waitcnt lgkmcnt(0)" ::: "memory");   // writes visible
        #pragma unroll 2
        for (int j4 = 0; j4 < cm; j4 += 4) {
            int j = j4 + q;
            bool ok = j < cm;
            int jj = ok ? j : 0;
            int s = __shfl(my_s, jj, 64);
            float ee = elds[w][epad(jj) + h];
            if (!ok) ee = 0.f;
            se += ee;
            bf16x8 hv = *(const bf16x8*)(h1b + (size_t)s * D1 + c8);
            #pragma unroll
            for (int i = 0; i < 8; ++i) ac[i] += ee * (float)hv[i];
        }
    }
    #pragma unroll
    for (int mk = 16; mk <= 32; mk <<= 1) {
        #pragma unroll
        for (int i = 0; i < 8; ++i) ac[i] += __shfl_xor(ac[i], mk, 64);
        se += __shfl_xor(se, mk, 64);
    }
    if (q == 0) {
        float inv = 1.f / (se + 1e-16f);
        bf16x8 r;
        #pragma unroll
        for (int i = 0; i < 8; ++i)
            r[i] = (__bf16)fmaxf(ac[i] * inv + b1[c8 + i], 0.f);
        *(bf16x8*)(r1b + (size_t)n * D1 + c8) = r;
    }
}

// ------- GEMM2 (MFMA) + fused att2 dots: h2b, as2, ad2 --------------------
__global__ __launch_bounds__(256) void k_gemm2(const __bf16* __restrict__ r1b,
                                               const __bf16* __restrict__ Wp2,
                                               const float* __restrict__ av2,
                                               const float* __restrict__ dv2,
                                               __bf16* __restrict__ h2b,
                                               float* __restrict__ as2,
                                               float* __restrict__ ad2) {
    __shared__ __align__(16) __bf16 As[128 * 128];  // 32KB, XOR-swizzled
    __shared__ __align__(16) __bf16 Bs[128 * 64];   // 16KB, packed+swizzled
    const int t = threadIdx.x;
    const int l = t & 63;
    const int w = t >> 6;
    const int wr = w * 32;
    const int n0 = blockIdx.x * 128;

    const uint4* gb = (const uint4*)Wp2;
    #pragma unroll
    for (int i = 0; i < 4; ++i) {
        int u = t + i * 256;
        uint4 d = gb[u];
        int u2 = u ^ ((u >> 6) & 3);
        *(uint4*)(Bs + u2 * 8) = d;
    }
    #pragma unroll
    for (int i = 0; i < 8; ++i) {
        int u = t + i * 256;
        int row = u >> 4, koff = (u & 15) * 8;
        bf16x8 v = {};
        if (n0 + row < N_NODES)
            v = *(const bf16x8*)(r1b + (size_t)(n0 + row) * D1 + koff);
        int eo = (row * 128 + koff) ^ ((row & 7) << 3);
        *(bf16x8*)(As + eo) = v;
    }
    __syncthreads();

    f32x4 acc[2][4];
    #pragma unroll
    for (int i = 0; i < 2; ++i)
        #pragma unroll
        for (int j = 0; j < 4; ++j) acc[i][j] = (f32x4){0.f, 0.f, 0.f, 0.f};

    #pragma unroll
    for (int ks = 0; ks < 4; ++ks) {
        bf16x8 af[2], bfr[4];
        #pragma unroll
        for (int fm = 0; fm < 2; ++fm) {
            int row = wr + fm * 16 + (l & 15);
            int eo = (row * 128 + ks * 32 + (l >> 4) * 8) ^ ((row & 7) << 3);
            af[fm] = *(const bf16x8*)(As + eo);
        }
        #pragma unroll
        for (int fn = 0; fn < 4; ++fn) {
            int col = fn * 16 + (l & 15);
            int kg = ks * 4 + (l >> 4);
            int u = (kg * 64 + col) ^ (kg & 3);
            bfr[fn] = *(const bf16x8*)(Bs + u * 8);
        }
        #pragma unroll
        for (int fm = 0; fm < 2; ++fm)
            #pragma unroll
            for (int fn = 0; fn < 4; ++fn)
                acc[fm][fn] = __builtin_amdgcn_mfma_f32_16x16x32_bf16(
                    af[fm], bfr[fn], acc[fm][fn], 0, 0, 0);
    }
    #pragma unroll
    for (int fm = 0; fm < 2; ++fm) {
        #pragma unroll
        for (int reg = 0; reg < 4; ++reg) {
            int row = n0 + wr + fm * 16 + (l >> 4) * 4 + reg;
            if (row >= N_NODES) continue;
            #pragma unroll
            for (int fn = 0; fn < 4; ++fn) {
                int col = fn * 16 + (l & 15);
                h2b[(size_t)row * D2 + col] = (__bf16)acc[fm][fn][reg];
            }
        }
    }
    // fused att2
    const int c16 = l & 15;
    float av[4], dv[4];
    #pragma unroll
    for (int fn = 0; fn < 4; ++fn) {
        av[fn] = av2[fn * 16 + c16];
        dv[fn] = dv2[fn * 16 + c16];
    }
    #pragma unroll
    for (int fm = 0; fm < 2; ++fm) {
        #pragma unroll
        for (int reg = 0; reg < 4; ++reg) {
            float vs = 0.f, vd = 0.f;
            #pragma unroll
            for (int fn = 0; fn < 4; ++fn) {
                vs += acc[fm][fn][reg] * av[fn];
                vd += acc[fm][fn][reg] * dv[fn];
            }
            #pragma unroll
            for (int mk = 1; mk <= 8; mk <<= 1) {
                vs += __shfl_xor(vs, mk, 64);
                vd += __shfl_xor(vd, mk, 64);
            }
            if (c16 == 0) {
                int row = n0 + wr + fm * 16 + (l >> 4) * 4 + reg;
                if (row < N_NODES) { as2[row] = vs; ad2[row] = vd; }
            }
        }
    }
}

// ------- aggregation layer 2: fused edge-exp + gather + log_softmax -------
__global__ __launch_bounds__(256) void k_agg2(const int* __restrict__ cnt,
                                              const int* __restrict__ srcs,
                                              const float* __restrict__ as2,
                                              const float* __restrict__ ad2,
                                              const __bf16* __restrict__ h2b,
                                              const float* __restrict__ b2,
                                              float* __restrict__ out) {
    const int w = threadIdx.x >> 6;
    const int l = threadIdx.x & 63;
    const int o = l >> 3;                      // edge slot within octet
    const int c8 = (l & 7) * 8;                // 8 channels per lane
    const int n = blockIdx.x * 4 + w;          // 12500 blocks exactly
    const int p0 = n * MAXD;
    const int m = min(cnt[n], MAXD);
    const float adn = ad2[n];
    float ac[8] = {0.f, 0.f, 0.f, 0.f, 0.f, 0.f, 0.f, 0.f};
    float se = 0.f;
    for (int base = 0; base < m; base += 64) {
        const int cm = min(64, m - base);
        int my_s = 0; float my_e = 0.f;
        if (l < cm) {
            my_s = srcs[p0 + base + l];
            float u = as2[my_s] + adn;
            u = (u > 0.f) ? u : 0.2f * u;
            my_e = __expf(u);
        }
        #pragma unroll 2
        for (int j8 = 0; j8 < cm; j8 += 8) {
            int j = j8 + o;
            bool ok = j < cm;
            int jj = ok ? j : 0;
            int s = __shfl(my_s, jj, 64);
            float ee = __shfl(my_e, jj, 64);
            if (!ok) ee = 0.f;
            se += ee;
            bf16x8 hv = *(const bf16x8*)(h2b + (size_t)s * D2 + c8);
            #pragma unroll
            for (int i = 0; i < 8; ++i) ac[i] += ee * (float)hv[i];
        }
    }
    #pragma unroll
    for (int mk = 8; mk <= 32; mk <<= 1) {
        #pragma unroll
        for (int i = 0; i < 8; ++i) ac[i] += __shfl_xor(ac[i], mk, 64);
        se += __shfl_xor(se, mk, 64);
    }
    float inv = 1.f / (se + 1e-16f);
    float v[8];
    #pragma unroll
    for (int i = 0; i < 8; ++i) v[i] = ac[i] * inv + b2[c8 + i];
    float mx = v[0];
    #pragma unroll
    for (int i = 1; i < 8; ++i) mx = fmaxf(mx, v[i]);
    #pragma unroll
    for (int mk = 1; mk <= 4; mk <<= 1) mx = fmaxf(mx, __shfl_xor(mx, mk, 64));
    float ex = 0.f;
    #pragma unroll
    for (int i = 0; i < 8; ++i) ex += __expf(v[i] - mx);
    #pragma unroll
    for (int mk = 1; mk <= 4; mk <<= 1) ex += __shfl_xor(ex, mk, 64);
    float lse = mx + __logf(ex);
    if (o == 0) {
        f32x4 r0 = {v[0] - lse, v[1] - lse, v[2] - lse, v[3] - lse};
        f32x4 r1 = {v[4] - lse, v[5] - lse, v[6] - lse, v[7] - lse};
        *(f32x4*)(out + (size_t)n * D2 + c8)     = r0;
        *(f32x4*)(out + (size_t)n * D2 + c8 + 4) = r1;
    }
}

extern "C" void kernel_launch(void* const* d_in, const int* in_sizes, int n_in,
                              void* d_out, int out_size, void* d_ws, size_t ws_size,
                              hipStream_t stream) {
    const float* x     = (const float*)d_in[0];
    const int*   ei    = (const int*)d_in[1];
    const float* W1    = (const float*)d_in[2];
    const float* asrc1 = (const float*)d_in[3];
    const float* adst1 = (const float*)d_in[4];
    const float* b1    = (const float*)d_in[5];
    const float* W2    = (const float*)d_in[6];
    const float* asrc2 = (const float*)d_in[7];
    const float* adst2 = (const float*)d_in[8];
    const float* b2    = (const float*)d_in[9];

    const int E  = in_sizes[1] / 2;   // 800000

    // ---- workspace layout ----
    __bf16* r1b = (__bf16*)d_ws;                        // N*128 bf16 (relu1)
    float* fw  = (float*)(r1b + (size_t)N_NODES * D1);
    float* as1  = fw;                                   // N*8
    float* ad1  = as1  + (size_t)N_NODES * H1;          // N*8
    float* as2  = ad1  + (size_t)N_NODES * H1;          // N
    float* ad2  = as2  + N_NODES;                       // N
    int* iw   = (int*)(ad2 + N_NODES);
    int* cnt  = iw;                                     // N
    int* srcs = cnt  + N_NODES;                         // N*MAXD (12.8 MB)
    uintptr_t pa = ((uintptr_t)(srcs + (size_t)N_NODES * MAXD) + 255) & ~(uintptr_t)255;
    __bf16* WpP  = (__bf16*)pa;                         // 512*128 bf16 (pre-swz)
    __bf16* Wp2  = WpP + (size_t)FIN * D1;              // 128*64 bf16
    __bf16* h1b  = Wp2 + (size_t)D1 * D2;               // N*128 bf16
    __bf16* h2b  = h1b + (size_t)N_NODES * D1;          // N*64 bf16

    k_prep   <<<FIN * D1 / 256, 256, 0, stream>>>(W1, W2, WpP, Wp2, cnt);
    k_mega   <<<GG + EB, 256, 0, stream>>>(x, WpP, asrc1, adst1, h1b, as1, ad1,
                                           ei, E, cnt, srcs);
    k_agg1   <<<N_NODES / 4, 256, 0, stream>>>(cnt, srcs, as1, ad1, h1b, b1, r1b);
    k_gemm2  <<<(N_NODES + 127) / 128, 256, 0, stream>>>(r1b, Wp2, asrc2, adst2, h2b, as2, ad2);
    k_agg2   <<<N_NODES / 4, 256, 0, stream>>>(cnt, srcs, as2, ad2, h2b, b2, (float*)d_out);
}